// Round 4
// baseline (889.091 us; speedup 1.0000x reference)
//
#include <hip/hip_runtime.h>

typedef __attribute__((ext_vector_type(8))) short short8;
typedef __attribute__((ext_vector_type(4))) float floatx4;

static constexpr int D = 1024;
static constexpr int F = 2048;
static constexpr int E = 8;
static constexpr int TOK = 4 * 2048;   // 8192 tokens
static constexpr int RTOT = 2 * TOK;   // 16384 expert-rows total (top-2 exact)

__device__ __forceinline__ unsigned short f2bf(float f) {
  unsigned int u = __float_as_uint(f);
  unsigned int r = (u + 0x7fffu + ((u >> 16) & 1u)) >> 16;  // RNE
  return (unsigned short)r;
}

__device__ __forceinline__ void glds16(const unsigned short* g, unsigned short* l) {
  __builtin_amdgcn_global_load_lds(
      (const __attribute__((address_space(1))) void*)g,
      (__attribute__((address_space(3))) void*)l, 16, 0, 0);
}

// meta layout (ints): [0:8)=cntp  [8:16)=cnts  [16:24)=pbase  [24:32)=sbase
//                     [32:40)=curp [40:48)=curs
// ---------------- router ----------------
__global__ __launch_bounds__(256) void router_kernel(
    const float* __restrict__ hs, const int* __restrict__ mask,
    const float* __restrict__ rw, int2* __restrict__ te, float2* __restrict__ tw,
    int* __restrict__ meta) {
  int t = blockIdx.x;
  const float* x = hs + (size_t)t * D;
  int tid = threadIdx.x;
  float acc[E];
#pragma unroll
  for (int e = 0; e < E; ++e) acc[e] = 0.f;
  for (int i = tid; i < D; i += 256) {
    float xv = x[i];
    const float4* r4 = (const float4*)(rw + (size_t)i * E);
    float4 ra = r4[0], rb = r4[1];
    acc[0] += xv * ra.x; acc[1] += xv * ra.y;
    acc[2] += xv * ra.z; acc[3] += xv * ra.w;
    acc[4] += xv * rb.x; acc[5] += xv * rb.y;
    acc[6] += xv * rb.z; acc[7] += xv * rb.w;
  }
#pragma unroll
  for (int e = 0; e < E; ++e) {
#pragma unroll
    for (int off = 32; off > 0; off >>= 1) acc[e] += __shfl_down(acc[e], off, 64);
  }
  __shared__ float red[4][E];
  int lane = tid & 63, wid = tid >> 6;
  if (lane == 0) {
#pragma unroll
    for (int e = 0; e < E; ++e) red[wid][e] = acc[e];
  }
  __syncthreads();
  if (tid == 0) {
    float lg[E];
#pragma unroll
    for (int e = 0; e < E; ++e) lg[e] = red[0][e] + red[1][e] + red[2][e] + red[3][e];
    int i1 = 0;
    for (int e = 1; e < E; ++e) if (lg[e] > lg[i1]) i1 = e;     // lowest argmax (jax tie rule)
    int i2 = (i1 == 0) ? 1 : 0;
    for (int e = 0; e < E; ++e) if (e != i1 && lg[e] > lg[i2]) i2 = e;
    float mx = fmaxf(lg[i1], lg[i2]);
    float e1 = expf(lg[i1] - mx), e2 = expf(lg[i2] - mx);
    float s = e1 + e2;
    float m = (mask[t] != 0) ? 1.f : 0.f;
    te[t] = make_int2(i1, i2);
    tw[t] = make_float2(e1 / s * m, e2 / s * m);
    atomicAdd(&meta[i1], 1);       // cntp
    atomicAdd(&meta[8 + i2], 1);   // cnts
  }
}

// ---------------- prefix (1 thread) ----------------
__global__ void prefix_kernel(int* __restrict__ meta) {
  int run = 0;
  for (int e = 0; e < E; ++e) {
    meta[16 + e] = run;                 // pbase
    meta[24 + e] = run + meta[e];       // sbase
    run += meta[e] + meta[8 + e];
  }
}

// ---------------- scatter: build LIST/WTS ----------------
__global__ __launch_bounds__(256) void scatter_kernel(
    const int2* __restrict__ te, const float2* __restrict__ tw,
    int* __restrict__ meta, int* __restrict__ LIST, float* __restrict__ WTS) {
  int t = blockIdx.x * 256 + threadIdx.x;
  int2 e = te[t];
  float2 w = tw[t];
  int s1 = meta[16 + e.x] + atomicAdd(&meta[32 + e.x], 1);
  LIST[s1] = t; WTS[s1] = w.x;
  int s2 = meta[24 + e.y] + atomicAdd(&meta[40 + e.y], 1);
  LIST[s2] = t; WTS[s2] = w.y;
}

// ---------------- fp32 -> bf16 conversion (X) ----------------
__global__ __launch_bounds__(256) void cvt_kernel(const float* __restrict__ in,
                                                  unsigned short* __restrict__ out) {
  size_t i = ((size_t)blockIdx.x * 256 + threadIdx.x) * 4;
  float4 v = *(const float4*)(in + i);
  union { unsigned short u[4]; uint2 q; } p;
  p.u[0] = f2bf(v.x); p.u[1] = f2bf(v.y); p.u[2] = f2bf(v.z); p.u[3] = f2bf(v.w);
  *(uint2*)(out + i) = p.q;
}

// ---------------- weight convert + transpose: src [e][K][N] fp32 -> dst [e][N][K] bf16 ----
__global__ __launch_bounds__(256) void cvtw_kernel(const float* __restrict__ src,
                                                   unsigned short* __restrict__ dst,
                                                   int K, int N) {
  int e = blockIdx.x, k0 = blockIdx.y * 64, n0 = blockIdx.z * 64;
  src += (size_t)e * K * N;
  dst += (size_t)e * K * N;
  __shared__ float t[64][65];
  int tid = threadIdx.x;
  int tr = tid >> 4, tc = (tid & 15) * 4;
#pragma unroll
  for (int i = 0; i < 4; ++i) {
    int k = tr + i * 16;
    float4 v = *(const float4*)(src + (size_t)(k0 + k) * N + n0 + tc);
    t[k][tc] = v.x; t[k][tc + 1] = v.y; t[k][tc + 2] = v.z; t[k][tc + 3] = v.w;
  }
  __syncthreads();
  int n = tid >> 2, kk = (tid & 3) * 16;
  union { unsigned short u[16]; uint4 q[2]; } p;
#pragma unroll
  for (int j = 0; j < 16; ++j) p.u[j] = f2bf(t[kk + j][n]);
  uint4* o = (uint4*)(dst + (size_t)(n0 + n) * K + k0 + kk);
  o[0] = p.q[0]; o[1] = p.q[1];
}

// ---------------- GEMM1 (fused over experts): Hc = relu(gather(X)*W1t[e]+b1[e]) --------
// BK=64 via two half-K LDS arrays (keeps the verified stride-64B ds_read pattern);
// A and B staged via global_load_lds width=16, no ds_writes.
__global__ __launch_bounds__(256) void gemm1_kernel(
    const unsigned short* __restrict__ X,    // [TOK, D] bf16
    const unsigned short* __restrict__ w1t,  // [E, F, D] bf16 (n-major)
    const float* __restrict__ b1,            // [E, F]
    const int* __restrict__ LIST,            // [RTOT]
    const int* __restrict__ meta,
    unsigned short* __restrict__ Hc) {       // [RTOT, F] bf16
  const int K = D, N = F;
  int e = blockIdx.x >> 6, m = blockIdx.x & 63;
  int cnt = meta[e] + meta[8 + e];
  int mrow = m * 128;
  if (mrow >= cnt) return;
  int rowStart = meta[16 + e] + mrow;
  int rowsLeft = cnt - mrow; if (rowsLeft > 128) rowsLeft = 128;

  __shared__ unsigned short As0[128 * 32], As1[128 * 32];  // k-chunks 0..31 / 32..63
  __shared__ unsigned short Bs0[128 * 32], Bs1[128 * 32];
  int n0 = blockIdx.y * 128;
  int tid = threadIdx.x;
  int lane = tid & 63, wid = tid >> 6;
  int wm = (wid >> 1) * 64, wn = (wid & 1) * 64;
  int lr = lane & 15, lq = lane >> 4;

  // staging geometry: wave wid covers LDS bytes [wid*1024, +1024) per half-tile; lane -> +lane*16
  int r0 = wid * 16 + (lane >> 2), r1 = 64 + r0;
  int kc = (lane & 3) * 8;
  int c0 = r0 < rowsLeft ? r0 : rowsLeft - 1;
  int c1 = r1 < rowsLeft ? r1 : rowsLeft - 1;
  const unsigned short* gA0 = X + (size_t)LIST[rowStart + c0] * K + kc;
  const unsigned short* gA1 = X + (size_t)LIST[rowStart + c1] * K + kc;
  const unsigned short* wb = w1t + (size_t)e * N * K;
  const unsigned short* gB0 = wb + (size_t)(n0 + r0) * K + kc;
  const unsigned short* gB1 = wb + (size_t)(n0 + r1) * K + kc;
  unsigned short* lA00 = &As0[r0 * 32 + kc]; unsigned short* lA01 = &As1[r0 * 32 + kc];
  unsigned short* lA10 = &As0[r1 * 32 + kc]; unsigned short* lA11 = &As1[r1 * 32 + kc];
  unsigned short* lB00 = &Bs0[r0 * 32 + kc]; unsigned short* lB01 = &Bs1[r0 * 32 + kc];
  unsigned short* lB10 = &Bs0[r1 * 32 + kc]; unsigned short* lB11 = &Bs1[r1 * 32 + kc];

  floatx4 acc[4][4];
#pragma unroll
  for (int i = 0; i < 4; ++i)
#pragma unroll
    for (int j = 0; j < 4; ++j) acc[i][j] = (floatx4){0.f, 0.f, 0.f, 0.f};

  for (int k0 = 0; k0 < K; k0 += 64) {
    __syncthreads();  // prior iteration's ds_reads complete
    glds16(gA0 + k0, lA00); glds16(gA0 + k0 + 32, lA01);
    glds16(gA1 + k0, lA10); glds16(gA1 + k0 + 32, lA11);
    glds16(gB0 + k0, lB00); glds16(gB0 + k0 + 32, lB01);
    glds16(gB1 + k0, lB10); glds16(gB1 + k0 + 32, lB11);
    __syncthreads();  // drains vmcnt (glds)
    short8 af[2][4], bfr[2][4];
#pragma unroll
    for (int i = 0; i < 4; ++i) {
      af[0][i] = *(const short8*)&As0[(wm + i * 16 + lr) * 32 + lq * 8];
      af[1][i] = *(const short8*)&As1[(wm + i * 16 + lr) * 32 + lq * 8];
    }
#pragma unroll
    for (int j = 0; j < 4; ++j) {
      bfr[0][j] = *(const short8*)&Bs0[(wn + j * 16 + lr) * 32 + lq * 8];
      bfr[1][j] = *(const short8*)&Bs1[(wn + j * 16 + lr) * 32 + lq * 8];
    }
#pragma unroll
    for (int h = 0; h < 2; ++h)
#pragma unroll
      for (int i = 0; i < 4; ++i)
#pragma unroll
        for (int j = 0; j < 4; ++j)
          acc[i][j] = __builtin_amdgcn_mfma_f32_16x16x32_bf16(af[h][i], bfr[h][j], acc[i][j], 0, 0, 0);
  }
  const float* be = b1 + (size_t)e * N;
#pragma unroll
  for (int i = 0; i < 4; ++i) {
#pragma unroll
    for (int j = 0; j < 4; ++j) {
      int col = n0 + wn + j * 16 + lr;
      float bias = be[col];
#pragma unroll
      for (int r = 0; r < 4; ++r) {
        int row = wm + i * 16 + lq * 4 + r;
        if (row < rowsLeft) {
          float v = fmaxf(acc[i][j][r] + bias, 0.f);
          Hc[(size_t)(rowStart + row) * N + col] = f2bf(v);
        }
      }
    }
  }
}

// ---------------- GEMM2 (fused, single pass): out[tok] += w * (Hc*W2t[e] + b2[e]) ------
__global__ __launch_bounds__(256) void gemm2_kernel(
    const unsigned short* __restrict__ Hc,   // [RTOT, F] bf16
    const unsigned short* __restrict__ w2t,  // [E, D, F] bf16 (n-major)
    const float* __restrict__ b2,            // [E, D]
    const int* __restrict__ LIST, const float* __restrict__ WTS,
    const int* __restrict__ meta,
    float* __restrict__ out) {               // [TOK, D] fp32, pre-zeroed
  const int K = F, N = D;
  int e = blockIdx.x >> 6, m = blockIdx.x & 63;
  int cnt = meta[e] + meta[8 + e];
  int mrow = m * 128;
  if (mrow >= cnt) return;
  int rowStart = meta[16 + e] + mrow;
  int rowsLeft = cnt - mrow; if (rowsLeft > 128) rowsLeft = 128;

  __shared__ unsigned short As0[128 * 32], As1[128 * 32];
  __shared__ unsigned short Bs0[128 * 32], Bs1[128 * 32];
  int n0 = blockIdx.y * 128;
  int tid = threadIdx.x;
  int lane = tid & 63, wid = tid >> 6;
  int wm = (wid >> 1) * 64, wn = (wid & 1) * 64;
  int lr = lane & 15, lq = lane >> 4;

  int r0 = wid * 16 + (lane >> 2), r1 = 64 + r0;
  int kc = (lane & 3) * 8;
  int c0 = r0 < rowsLeft ? r0 : rowsLeft - 1;
  int c1 = r1 < rowsLeft ? r1 : rowsLeft - 1;
  const unsigned short* gA0 = Hc + (size_t)(rowStart + c0) * K + kc;
  const unsigned short* gA1 = Hc + (size_t)(rowStart + c1) * K + kc;
  const unsigned short* wb = w2t + (size_t)e * N * K;
  const unsigned short* gB0 = wb + (size_t)(n0 + r0) * K + kc;
  const unsigned short* gB1 = wb + (size_t)(n0 + r1) * K + kc;
  unsigned short* lA00 = &As0[r0 * 32 + kc]; unsigned short* lA01 = &As1[r0 * 32 + kc];
  unsigned short* lA10 = &As0[r1 * 32 + kc]; unsigned short* lA11 = &As1[r1 * 32 + kc];
  unsigned short* lB00 = &Bs0[r0 * 32 + kc]; unsigned short* lB01 = &Bs1[r0 * 32 + kc];
  unsigned short* lB10 = &Bs0[r1 * 32 + kc]; unsigned short* lB11 = &Bs1[r1 * 32 + kc];

  floatx4 acc[4][4];
#pragma unroll
  for (int i = 0; i < 4; ++i)
#pragma unroll
    for (int j = 0; j < 4; ++j) acc[i][j] = (floatx4){0.f, 0.f, 0.f, 0.f};

  for (int k0 = 0; k0 < K; k0 += 64) {
    __syncthreads();
    glds16(gA0 + k0, lA00); glds16(gA0 + k0 + 32, lA01);
    glds16(gA1 + k0, lA10); glds16(gA1 + k0 + 32, lA11);
    glds16(gB0 + k0, lB00); glds16(gB0 + k0 + 32, lB01);
    glds16(gB1 + k0, lB10); glds16(gB1 + k0 + 32, lB11);
    __syncthreads();
    short8 af[2][4], bfr[2][4];
#pragma unroll
    for (int i = 0; i < 4; ++i) {
      af[0][i] = *(const short8*)&As0[(wm + i * 16 + lr) * 32 + lq * 8];
      af[1][i] = *(const short8*)&As1[(wm + i * 16 + lr) * 32 + lq * 8];
    }
#pragma unroll
    for (int j = 0; j < 4; ++j) {
      bfr[0][j] = *(const short8*)&Bs0[(wn + j * 16 + lr) * 32 + lq * 8];
      bfr[1][j] = *(const short8*)&Bs1[(wn + j * 16 + lr) * 32 + lq * 8];
    }
#pragma unroll
    for (int h = 0; h < 2; ++h)
#pragma unroll
      for (int i = 0; i < 4; ++i)
#pragma unroll
        for (int j = 0; j < 4; ++j)
          acc[i][j] = __builtin_amdgcn_mfma_f32_16x16x32_bf16(af[h][i], bfr[h][j], acc[i][j], 0, 0, 0);
  }
  const float* be = b2 + (size_t)e * N;
#pragma unroll
  for (int i = 0; i < 4; ++i) {
    int tokr[4]; float wtr[4]; bool val[4];
#pragma unroll
    for (int r = 0; r < 4; ++r) {
      int row = wm + i * 16 + lq * 4 + r;
      val[r] = row < rowsLeft;
      int gi = rowStart + (val[r] ? row : 0);
      tokr[r] = LIST[gi]; wtr[r] = WTS[gi];
    }
#pragma unroll
    for (int j = 0; j < 4; ++j) {
      int col = n0 + wn + j * 16 + lr;
      float bias = be[col];
#pragma unroll
      for (int r = 0; r < 4; ++r) {
        if (val[r]) {
          atomicAdd(&out[(size_t)tokr[r] * N + col], wtr[r] * (acc[i][j][r] + bias));
        }
      }
    }
  }
}

extern "C" void kernel_launch(void* const* d_in, const int* in_sizes, int n_in,
                              void* d_out, int out_size, void* d_ws, size_t ws_size,
                              hipStream_t stream) {
  (void)in_sizes; (void)n_in; (void)ws_size;
  const float* hs   = (const float*)d_in[0];
  const int*   mask = (const int*)d_in[1];
  const float* rw   = (const float*)d_in[2];
  const float* w1   = (const float*)d_in[3];
  const float* b1   = (const float*)d_in[4];
  const float* w2   = (const float*)d_in[5];
  const float* b2   = (const float*)d_in[6];
  float* out = (float*)d_out;

  char* ws = (char*)d_ws;
  int* meta  = (int*)ws;
  int2* te   = (int2*)(ws + 1024);
  float2* tw = (float2*)(ws + 1024 + (size_t)TOK * 8);
  int* LIST  = (int*)(ws + 1024 + (size_t)TOK * 16);
  float* WTS = (float*)(ws + 1024 + (size_t)TOK * 16 + (size_t)RTOT * 4);
  unsigned short* Xbf = (unsigned short*)(ws + (1 << 20));                        // 16 MB
  unsigned short* Hc  = (unsigned short*)(ws + (1 << 20) + (size_t)TOK * D * 2);  // 64 MB
  unsigned short* Wt  = (unsigned short*)(ws + (1 << 20) + (size_t)TOK * D * 2 +
                                          (size_t)RTOT * F * 2);                  // 32 MB (reused)

  hipMemsetAsync(meta, 0, 256, stream);
  hipMemsetAsync(out, 0, (size_t)out_size * sizeof(float), stream);
  router_kernel<<<TOK, 256, 0, stream>>>(hs, mask, rw, te, tw, meta);
  prefix_kernel<<<1, 1, 0, stream>>>(meta);
  scatter_kernel<<<TOK / 256, 256, 0, stream>>>(te, tw, meta, LIST, WTS);
  cvt_kernel<<<(TOK * D / 4) / 256, 256, 0, stream>>>(hs, Xbf);
  // w1 [E][D][F] -> Wt [E][F][D] bf16
  cvtw_kernel<<<dim3(E, D / 64, F / 64), 256, 0, stream>>>(w1, Wt, D, F);
  gemm1_kernel<<<dim3(E * 64, F / 128), 256, 0, stream>>>(Xbf, Wt, b1, LIST, meta, Hc);
  // w2 [E][F][D] -> Wt [E][D][F] bf16 (reuses the same buffer after gemm1)
  cvtw_kernel<<<dim3(E, F / 64, D / 64), 256, 0, stream>>>(w2, Wt, F, D);
  gemm2_kernel<<<dim3(E * 64, D / 128), 256, 0, stream>>>(Hc, Wt, b2, LIST, WTS, meta, out);
}

// Round 5
// 701.699 us; speedup vs baseline: 1.2671x; 1.2671x over previous
//
#include <hip/hip_runtime.h>

typedef __attribute__((ext_vector_type(8))) short short8;
typedef __attribute__((ext_vector_type(4))) float floatx4;

static constexpr int D = 1024;
static constexpr int F = 2048;
static constexpr int E = 8;
static constexpr int TOK = 4 * 2048;   // 8192 tokens
static constexpr int RTOT = 2 * TOK;   // 16384 expert-rows total (top-2 exact)
static constexpr int MT = 24;          // m-tiles per expert (3072 rows >> mean 2048)

__device__ __forceinline__ unsigned short f2bf(float f) {
  unsigned int u = __float_as_uint(f);
  unsigned int r = (u + 0x7fffu + ((u >> 16) & 1u)) >> 16;  // RNE
  return (unsigned short)r;
}

__device__ __forceinline__ void glds16(const unsigned short* g, unsigned short* l) {
  __builtin_amdgcn_global_load_lds(
      (const __attribute__((address_space(1))) void*)g,
      (__attribute__((address_space(3))) void*)l, 16, 0, 0);
}

// meta layout (ints): [0:8)=cntp  [8:16)=cnts  [16:24)=pbase  [24:32)=sbase
//                     [32:40)=curp [40:48)=curs
// ---------------- router ----------------
__global__ __launch_bounds__(256) void router_kernel(
    const float* __restrict__ hs, const int* __restrict__ mask,
    const float* __restrict__ rw, int2* __restrict__ te, float2* __restrict__ tw,
    int* __restrict__ meta) {
  int t = blockIdx.x;
  const float* x = hs + (size_t)t * D;
  int tid = threadIdx.x;
  float acc[E];
#pragma unroll
  for (int e = 0; e < E; ++e) acc[e] = 0.f;
  for (int i = tid; i < D; i += 256) {
    float xv = x[i];
    const float4* r4 = (const float4*)(rw + (size_t)i * E);
    float4 ra = r4[0], rb = r4[1];
    acc[0] += xv * ra.x; acc[1] += xv * ra.y;
    acc[2] += xv * ra.z; acc[3] += xv * ra.w;
    acc[4] += xv * rb.x; acc[5] += xv * rb.y;
    acc[6] += xv * rb.z; acc[7] += xv * rb.w;
  }
#pragma unroll
  for (int e = 0; e < E; ++e) {
#pragma unroll
    for (int off = 32; off > 0; off >>= 1) acc[e] += __shfl_down(acc[e], off, 64);
  }
  __shared__ float red[4][E];
  int lane = tid & 63, wid = tid >> 6;
  if (lane == 0) {
#pragma unroll
    for (int e = 0; e < E; ++e) red[wid][e] = acc[e];
  }
  __syncthreads();
  if (tid == 0) {
    float lg[E];
#pragma unroll
    for (int e = 0; e < E; ++e) lg[e] = red[0][e] + red[1][e] + red[2][e] + red[3][e];
    int i1 = 0;
    for (int e = 1; e < E; ++e) if (lg[e] > lg[i1]) i1 = e;     // lowest argmax (jax tie rule)
    int i2 = (i1 == 0) ? 1 : 0;
    for (int e = 0; e < E; ++e) if (e != i1 && lg[e] > lg[i2]) i2 = e;
    float mx = fmaxf(lg[i1], lg[i2]);
    float e1 = expf(lg[i1] - mx), e2 = expf(lg[i2] - mx);
    float s = e1 + e2;
    float m = (mask[t] != 0) ? 1.f : 0.f;
    te[t] = make_int2(i1, i2);
    tw[t] = make_float2(e1 / s * m, e2 / s * m);
    atomicAdd(&meta[i1], 1);       // cntp
    atomicAdd(&meta[8 + i2], 1);   // cnts
  }
}

// ---------------- prefix (1 thread) ----------------
__global__ void prefix_kernel(int* __restrict__ meta) {
  int run = 0;
  for (int e = 0; e < E; ++e) {
    meta[16 + e] = run;                 // pbase
    meta[24 + e] = run + meta[e];       // sbase
    run += meta[e] + meta[8 + e];
  }
}

// ---------------- scatter: build LIST/WTS ----------------
__global__ __launch_bounds__(256) void scatter_kernel(
    const int2* __restrict__ te, const float2* __restrict__ tw,
    int* __restrict__ meta, int* __restrict__ LIST, float* __restrict__ WTS) {
  int t = blockIdx.x * 256 + threadIdx.x;
  int2 e = te[t];
  float2 w = tw[t];
  int s1 = meta[16 + e.x] + atomicAdd(&meta[32 + e.x], 1);
  LIST[s1] = t; WTS[s1] = w.x;
  int s2 = meta[24 + e.y] + atomicAdd(&meta[40 + e.y], 1);
  LIST[s2] = t; WTS[s2] = w.y;
}

// ---------------- fp32 -> bf16 conversion (X) ----------------
__global__ __launch_bounds__(256) void cvt_kernel(const float* __restrict__ in,
                                                  unsigned short* __restrict__ out) {
  size_t i = ((size_t)blockIdx.x * 256 + threadIdx.x) * 4;
  float4 v = *(const float4*)(in + i);
  union { unsigned short u[4]; uint2 q; } p;
  p.u[0] = f2bf(v.x); p.u[1] = f2bf(v.y); p.u[2] = f2bf(v.z); p.u[3] = f2bf(v.w);
  *(uint2*)(out + i) = p.q;
}

// ---------------- weight convert + transpose: src [e][K][N] fp32 -> dst [e][N][K] bf16 ----
__global__ __launch_bounds__(256) void cvtw_kernel(const float* __restrict__ src,
                                                   unsigned short* __restrict__ dst,
                                                   int K, int N) {
  int e = blockIdx.x, k0 = blockIdx.y * 64, n0 = blockIdx.z * 64;
  src += (size_t)e * K * N;
  dst += (size_t)e * K * N;
  __shared__ float t[64][65];
  int tid = threadIdx.x;
  int tr = tid >> 4, tc = (tid & 15) * 4;
#pragma unroll
  for (int i = 0; i < 4; ++i) {
    int k = tr + i * 16;
    float4 v = *(const float4*)(src + (size_t)(k0 + k) * N + n0 + tc);
    t[k][tc] = v.x; t[k][tc + 1] = v.y; t[k][tc + 2] = v.z; t[k][tc + 3] = v.w;
  }
  __syncthreads();
  int n = tid >> 2, kk = (tid & 3) * 16;
  union { unsigned short u[16]; uint4 q[2]; } p;
#pragma unroll
  for (int j = 0; j < 16; ++j) p.u[j] = f2bf(t[kk + j][n]);
  uint4* o = (uint4*)(dst + (size_t)(n0 + n) * K + k0 + kk);
  o[0] = p.q[0]; o[1] = p.q[1];
}

// ---------------- GEMM1: Hc = relu(gather(X)*W1t[e]+b1[e]) --------
// 1-D grid, e = blockIdx.x%8 -> XCD pinning (W1t[e] = 4MB = one XCD L2).
// n-fastest tile order so co-resident blocks on an XCD cover all n (full W reuse).
__global__ __launch_bounds__(256) void gemm1_kernel(
    const unsigned short* __restrict__ X,    // [TOK, D] bf16
    const unsigned short* __restrict__ w1t,  // [E, F, D] bf16 (n-major)
    const float* __restrict__ b1,            // [E, F]
    const int* __restrict__ LIST,            // [RTOT]
    const int* __restrict__ meta,
    unsigned short* __restrict__ Hc) {       // [RTOT, F] bf16
  const int K = D, N = F;
  int bx = blockIdx.x;
  int e = bx & 7;
  int t = bx >> 3;
  int n0 = (t & 15) * 128;   // n-fastest
  int m = t >> 4;            // 0..MT-1
  int cnt = meta[e] + meta[8 + e];
  int mrow = m * 128;
  if (mrow >= cnt) return;
  int rowStart = meta[16 + e] + mrow;
  int rowsLeft = cnt - mrow; if (rowsLeft > 128) rowsLeft = 128;

  __shared__ unsigned short As[128 * 32];  // [m][k] unpadded (glds layout)
  __shared__ unsigned short Bs[128 * 32];  // [n][k] unpadded (glds layout)
  int tid = threadIdx.x;
  int lane = tid & 63, wid = tid >> 6;
  int wm = (wid >> 1) * 64, wn = (wid & 1) * 64;
  int lr = lane & 15, lq = lane >> 4;

  int r0 = wid * 16 + (lane >> 2), r1 = 64 + r0;
  int kc = (lane & 3) * 8;
  int c0 = r0 < rowsLeft ? r0 : rowsLeft - 1;
  int c1 = r1 < rowsLeft ? r1 : rowsLeft - 1;
  const unsigned short* gA0 = X + (size_t)LIST[rowStart + c0] * K + kc;
  const unsigned short* gA1 = X + (size_t)LIST[rowStart + c1] * K + kc;
  const unsigned short* wb = w1t + (size_t)e * N * K;
  const unsigned short* gB0 = wb + (size_t)(n0 + r0) * K + kc;
  const unsigned short* gB1 = wb + (size_t)(n0 + r1) * K + kc;
  unsigned short* lA0 = &As[r0 * 32 + kc];
  unsigned short* lA1 = &As[r1 * 32 + kc];
  unsigned short* lB0 = &Bs[r0 * 32 + kc];
  unsigned short* lB1 = &Bs[r1 * 32 + kc];

  floatx4 acc[4][4];
#pragma unroll
  for (int i = 0; i < 4; ++i)
#pragma unroll
    for (int j = 0; j < 4; ++j) acc[i][j] = (floatx4){0.f, 0.f, 0.f, 0.f};

  for (int k0 = 0; k0 < K; k0 += 32) {
    __syncthreads();
    glds16(gA0 + k0, lA0);
    glds16(gA1 + k0, lA1);
    glds16(gB0 + k0, lB0);
    glds16(gB1 + k0, lB1);
    __syncthreads();
    short8 af[4], bfr[4];
#pragma unroll
    for (int i = 0; i < 4; ++i)
      af[i] = *(const short8*)&As[(wm + i * 16 + lr) * 32 + lq * 8];
#pragma unroll
    for (int j = 0; j < 4; ++j)
      bfr[j] = *(const short8*)&Bs[(wn + j * 16 + lr) * 32 + lq * 8];
#pragma unroll
    for (int i = 0; i < 4; ++i)
#pragma unroll
      for (int j = 0; j < 4; ++j)
        acc[i][j] = __builtin_amdgcn_mfma_f32_16x16x32_bf16(af[i], bfr[j], acc[i][j], 0, 0, 0);
  }
  const float* be = b1 + (size_t)e * N;
#pragma unroll
  for (int i = 0; i < 4; ++i) {
#pragma unroll
    for (int j = 0; j < 4; ++j) {
      int col = n0 + wn + j * 16 + lr;
      float bias = be[col];
#pragma unroll
      for (int r = 0; r < 4; ++r) {
        int row = wm + i * 16 + lq * 4 + r;
        if (row < rowsLeft) {
          float v = fmaxf(acc[i][j][r] + bias, 0.f);
          Hc[(size_t)(rowStart + row) * N + col] = f2bf(v);
        }
      }
    }
  }
}

// ---------------- GEMM2: out[tok] += w * (Hc*W2t[e] + b2[e]) ------
__global__ __launch_bounds__(256) void gemm2_kernel(
    const unsigned short* __restrict__ Hc,   // [RTOT, F] bf16
    const unsigned short* __restrict__ w2t,  // [E, D, F] bf16 (n-major)
    const float* __restrict__ b2,            // [E, D]
    const int* __restrict__ LIST, const float* __restrict__ WTS,
    const int* __restrict__ meta,
    float* __restrict__ out) {               // [TOK, D] fp32, pre-zeroed
  const int K = F, N = D;
  int bx = blockIdx.x;
  int e = bx & 7;
  int t = bx >> 3;
  int n0 = (t & 7) * 128;    // n-fastest
  int m = t >> 3;
  int cnt = meta[e] + meta[8 + e];
  int mrow = m * 128;
  if (mrow >= cnt) return;
  int rowStart = meta[16 + e] + mrow;
  int rowsLeft = cnt - mrow; if (rowsLeft > 128) rowsLeft = 128;

  __shared__ unsigned short As[128 * 32];
  __shared__ unsigned short Bs[128 * 32];
  int tid = threadIdx.x;
  int lane = tid & 63, wid = tid >> 6;
  int wm = (wid >> 1) * 64, wn = (wid & 1) * 64;
  int lr = lane & 15, lq = lane >> 4;

  int r0 = wid * 16 + (lane >> 2), r1 = 64 + r0;
  int kc = (lane & 3) * 8;
  int c0 = r0 < rowsLeft ? r0 : rowsLeft - 1;
  int c1 = r1 < rowsLeft ? r1 : rowsLeft - 1;
  const unsigned short* gA0 = Hc + (size_t)(rowStart + c0) * K + kc;
  const unsigned short* gA1 = Hc + (size_t)(rowStart + c1) * K + kc;
  const unsigned short* wb = w2t + (size_t)e * N * K;
  const unsigned short* gB0 = wb + (size_t)(n0 + r0) * K + kc;
  const unsigned short* gB1 = wb + (size_t)(n0 + r1) * K + kc;
  unsigned short* lA0 = &As[r0 * 32 + kc];
  unsigned short* lA1 = &As[r1 * 32 + kc];
  unsigned short* lB0 = &Bs[r0 * 32 + kc];
  unsigned short* lB1 = &Bs[r1 * 32 + kc];

  floatx4 acc[4][4];
#pragma unroll
  for (int i = 0; i < 4; ++i)
#pragma unroll
    for (int j = 0; j < 4; ++j) acc[i][j] = (floatx4){0.f, 0.f, 0.f, 0.f};

  for (int k0 = 0; k0 < K; k0 += 32) {
    __syncthreads();
    glds16(gA0 + k0, lA0);
    glds16(gA1 + k0, lA1);
    glds16(gB0 + k0, lB0);
    glds16(gB1 + k0, lB1);
    __syncthreads();
    short8 af[4], bfr[4];
#pragma unroll
    for (int i = 0; i < 4; ++i)
      af[i] = *(const short8*)&As[(wm + i * 16 + lr) * 32 + lq * 8];
#pragma unroll
    for (int j = 0; j < 4; ++j)
      bfr[j] = *(const short8*)&Bs[(wn + j * 16 + lr) * 32 + lq * 8];
#pragma unroll
    for (int i = 0; i < 4; ++i)
#pragma unroll
      for (int j = 0; j < 4; ++j)
        acc[i][j] = __builtin_amdgcn_mfma_f32_16x16x32_bf16(af[i], bfr[j], acc[i][j], 0, 0, 0);
  }
  const float* be = b2 + (size_t)e * N;
#pragma unroll
  for (int i = 0; i < 4; ++i) {
    int tokr[4]; float wtr[4]; bool val[4];
#pragma unroll
    for (int r = 0; r < 4; ++r) {
      int row = wm + i * 16 + lq * 4 + r;
      val[r] = row < rowsLeft;
      int gi = rowStart + (val[r] ? row : 0);
      tokr[r] = LIST[gi]; wtr[r] = WTS[gi];
    }
#pragma unroll
    for (int j = 0; j < 4; ++j) {
      int col = n0 + wn + j * 16 + lr;
      float bias = be[col];
#pragma unroll
      for (int r = 0; r < 4; ++r) {
        if (val[r]) {
          atomicAdd(&out[(size_t)tokr[r] * N + col], wtr[r] * (acc[i][j][r] + bias));
        }
      }
    }
  }
}

extern "C" void kernel_launch(void* const* d_in, const int* in_sizes, int n_in,
                              void* d_out, int out_size, void* d_ws, size_t ws_size,
                              hipStream_t stream) {
  (void)in_sizes; (void)n_in; (void)ws_size;
  const float* hs   = (const float*)d_in[0];
  const int*   mask = (const int*)d_in[1];
  const float* rw   = (const float*)d_in[2];
  const float* w1   = (const float*)d_in[3];
  const float* b1   = (const float*)d_in[4];
  const float* w2   = (const float*)d_in[5];
  const float* b2   = (const float*)d_in[6];
  float* out = (float*)d_out;

  char* ws = (char*)d_ws;
  int* meta  = (int*)ws;
  int2* te   = (int2*)(ws + 1024);
  float2* tw = (float2*)(ws + 1024 + (size_t)TOK * 8);
  int* LIST  = (int*)(ws + 1024 + (size_t)TOK * 16);
  float* WTS = (float*)(ws + 1024 + (size_t)TOK * 16 + (size_t)RTOT * 4);
  unsigned short* Xbf = (unsigned short*)(ws + (1 << 20));                        // 16 MB
  unsigned short* Hc  = (unsigned short*)(ws + (1 << 20) + (size_t)TOK * D * 2);  // 64 MB
  unsigned short* Wt  = (unsigned short*)(ws + (1 << 20) + (size_t)TOK * D * 2 +
                                          (size_t)RTOT * F * 2);                  // 32 MB (reused)

  hipMemsetAsync(meta, 0, 256, stream);
  hipMemsetAsync(out, 0, (size_t)out_size * sizeof(float), stream);
  router_kernel<<<TOK, 256, 0, stream>>>(hs, mask, rw, te, tw, meta);
  prefix_kernel<<<1, 1, 0, stream>>>(meta);
  scatter_kernel<<<TOK / 256, 256, 0, stream>>>(te, tw, meta, LIST, WTS);
  cvt_kernel<<<(TOK * D / 4) / 256, 256, 0, stream>>>(hs, Xbf);
  // w1 [E][D][F] -> Wt [E][F][D] bf16
  cvtw_kernel<<<dim3(E, D / 64, F / 64), 256, 0, stream>>>(w1, Wt, D, F);
  gemm1_kernel<<<E * MT * (F / 128), 256, 0, stream>>>(Xbf, Wt, b1, LIST, meta, Hc);
  // w2 [E][F][D] -> Wt [E][D][F] bf16 (reuses the same buffer after gemm1)
  cvtw_kernel<<<dim3(E, F / 64, D / 64), 256, 0, stream>>>(w2, Wt, F, D);
  gemm2_kernel<<<E * MT * (D / 128), 256, 0, stream>>>(Hc, Wt, b2, LIST, WTS, meta, out);
}